// Round 3
// baseline (88.629 us; speedup 1.0000x reference)
//
#include <hip/hip_runtime.h>
#include <hip/hip_bf16.h>

#define IN_CH 256
#define OUT_CH 256
#define N_TASKS 64
#define W_SIZE (OUT_CH * IN_CH)          // 65536
#define FULL_EMBED (W_SIZE + OUT_CH)     // 65792
#define THREADS 256
#define NCOLT 16                         // 16 col tiles of 16 outputs
#define BUCKET_CAP 4096                  // worst case: all rows one task

typedef __attribute__((ext_vector_type(8))) short bf16x8;
typedef __attribute__((ext_vector_type(4))) float f32x4;

static __device__ __forceinline__ short f2bf(float f) {
    union { __hip_bfloat16 h; short s; } u;
    u.h = __float2bfloat16(f);
    return u.s;
}

static __device__ __forceinline__ bf16x8 cvt8(f32x4 a, f32x4 b) {
    bf16x8 r;
    r[0] = f2bf(a.x); r[1] = f2bf(a.y); r[2] = f2bf(a.z); r[3] = f2bf(a.w);
    r[4] = f2bf(b.x); r[5] = f2bf(b.y); r[6] = f2bf(b.z); r[7] = f2bf(b.w);
    return r;
}

// ws layout: [0,64)   = per-task counts
//            [64, ...)= 64 buckets of BUCKET_CAP row indices each
__global__ __launch_bounds__(1024) void bucket_kernel(
    const int* __restrict__ tids, int* __restrict__ ws, int B)
{
    __shared__ int scnt[N_TASKS];
    const int tid = threadIdx.x;
    if (tid < N_TASKS) scnt[tid] = 0;
    __syncthreads();

    int* __restrict__ rows = ws + N_TASKS;
    for (int i0 = tid * 4; i0 < B; i0 += 4096) {
        int4 v = *reinterpret_cast<const int4*>(tids + i0);
        int p;
        p = atomicAdd(&scnt[v.x], 1); rows[v.x * BUCKET_CAP + p] = i0;
        p = atomicAdd(&scnt[v.y], 1); rows[v.y * BUCKET_CAP + p] = i0 + 1;
        p = atomicAdd(&scnt[v.z], 1); rows[v.z * BUCKET_CAP + p] = i0 + 2;
        p = atomicAdd(&scnt[v.w], 1); rows[v.w * BUCKET_CAP + p] = i0 + 3;
    }
    __syncthreads();
    if (tid < N_TASKS) ws[tid] = scnt[tid];
}

__global__ __launch_bounds__(THREADS, 4) void mtal_mfma(
    const float* __restrict__ x, const float* __restrict__ emb,
    const int* __restrict__ ws, float* __restrict__ out)
{
    // XCD-aware decode: blocks of the same task are stride-64 apart
    // -> same bid%8 -> same XCD -> W_t and x rows stay in one L2.
    const int bid = blockIdx.x;
    const int t   = bid & 63;           // task id
    const int ct  = bid >> 6;           // col tile (16 outputs)

    const int lane  = threadIdx.x & 63;
    const int wv    = threadIdx.x >> 6; // wave 0..3, splits row tiles
    const int l15   = lane & 15;
    const int khalf = lane >> 4;        // 0..3
    const int col   = ct * 16 + l15;

    const float* __restrict__ wbase = emb + (size_t)t * FULL_EMBED;

    // B fragments: W[col][k], k = ks*32 + khalf*8 + j (32B contiguous/lane).
    const float* __restrict__ wp = wbase + (size_t)col * IN_CH + khalf * 8;
    bf16x8 wf[8];
#pragma unroll
    for (int ks = 0; ks < 8; ++ks) {
        f32x4 a = *reinterpret_cast<const f32x4*>(wp + ks * 32);
        f32x4 b = *reinterpret_cast<const f32x4*>(wp + ks * 32 + 4);
        wf[ks] = cvt8(a, b);
    }
    const float biasv = wbase[W_SIZE + col];

    const int n = ws[t];                // uniform -> s_load
    if (n == 0) return;
    const int* __restrict__ rows = ws + N_TASKS + t * BUCKET_CAP;

    const int nt = (n + 15) >> 4;       // row tiles of 16
    for (int rt = wv; rt < nt; rt += 4) {
        const int ridx = rt * 16 + l15;
        const int row  = rows[ridx < n ? ridx : 0];   // clamp dup for tail
        const float* __restrict__ xr = x + (size_t)row * IN_CH + khalf * 8;

        bf16x8 af[8];
#pragma unroll
        for (int ks = 0; ks < 8; ++ks) {
            f32x4 a = *reinterpret_cast<const f32x4*>(xr + ks * 32);
            f32x4 b = *reinterpret_cast<const f32x4*>(xr + ks * 32 + 4);
            af[ks] = cvt8(a, b);
        }

        f32x4 acc = { biasv, biasv, biasv, biasv };
#pragma unroll
        for (int ks = 0; ks < 8; ++ks)
            acc = __builtin_amdgcn_mfma_f32_16x16x32_bf16(af[ks], wf[ks], acc, 0, 0, 0);

        // D layout: col = lane&15, row = khalf*4 + reg (verified m89 mapping).
        const int m0 = rt * 16 + khalf * 4;
#pragma unroll
        for (int r = 0; r < 4; ++r) {
            const int gm = m0 + r;
            // row index for gm is held by lane l15 == khalf*4 + r (same tile)
            const int grow = __shfl(row, khalf * 4 + r, 16);
            if (gm < n)
                out[(size_t)grow * OUT_CH + col] = acc[r];
        }
    }
}

extern "C" void kernel_launch(void* const* d_in, const int* in_sizes, int n_in,
                              void* d_out, int out_size, void* d_ws, size_t ws_size,
                              hipStream_t stream) {
    const float* x    = (const float*)d_in[0];
    const int*   tids = (const int*)d_in[1];
    const float* emb  = (const float*)d_in[2];
    float*       out  = (float*)d_out;
    int*         ws   = (int*)d_ws;
    const int B = in_sizes[1];   // 4096

    bucket_kernel<<<dim3(1), dim3(1024), 0, stream>>>(tids, ws, B);
    mtal_mfma<<<dim3(N_TASKS * NCOLT), dim3(THREADS), 0, stream>>>(
        x, emb, ws, out);
}

// Round 4
// 87.136 us; speedup vs baseline: 1.0171x; 1.0171x over previous
//
#include <hip/hip_runtime.h>
#include <hip/hip_bf16.h>

#define IN_CH 256
#define OUT_CH 256
#define N_TASKS 64
#define W_SIZE (OUT_CH * IN_CH)          // 65536
#define FULL_EMBED (W_SIZE + OUT_CH)     // 65792
#define THREADS 256
#define NCOLT 16                         // 16 col tiles of 16 outputs
#define BUCKET_CAP 4096                  // worst case: all rows one task

typedef __attribute__((ext_vector_type(8))) short bf16x8;
typedef __attribute__((ext_vector_type(4))) float f32x4;

static __device__ __forceinline__ short f2bf(float f) {
    union { __hip_bfloat16 h; short s; } u;
    u.h = __float2bfloat16(f);
    return u.s;
}

static __device__ __forceinline__ bf16x8 cvt8(f32x4 a, f32x4 b) {
    bf16x8 r;
    r[0] = f2bf(a.x); r[1] = f2bf(a.y); r[2] = f2bf(a.z); r[3] = f2bf(a.w);
    r[4] = f2bf(b.x); r[5] = f2bf(b.y); r[6] = f2bf(b.z); r[7] = f2bf(b.w);
    return r;
}

// ws layout: [0,64)   = per-task counts
//            [64,...) = 64 buckets of BUCKET_CAP row indices each
// 64 blocks, block t gathers rows of task t. Ballot compaction: one LDS
// atomic per wave instead of ~64 serialized same-address atomics.
__global__ __launch_bounds__(256) void bucket_kernel(
    const int* __restrict__ tids, int* __restrict__ ws, int B)
{
    __shared__ int cnt;
    const int t    = blockIdx.x;
    const int tid  = threadIdx.x;
    const int lane = tid & 63;
    if (tid == 0) cnt = 0;
    __syncthreads();

    // 16 ids per thread, 4 independent coalesced int4 loads (one latency round)
    int4 v[4];
#pragma unroll
    for (int u = 0; u < 4; ++u)
        v[u] = reinterpret_cast<const int4*>(tids)[tid + 256 * u];

    unsigned long long mask[16];
    int off[16];
    int cum = 0;
#pragma unroll
    for (int u = 0; u < 4; ++u) {
        mask[4 * u + 0] = __ballot(v[u].x == t);
        mask[4 * u + 1] = __ballot(v[u].y == t);
        mask[4 * u + 2] = __ballot(v[u].z == t);
        mask[4 * u + 3] = __ballot(v[u].w == t);
    }
#pragma unroll
    for (int j = 0; j < 16; ++j) { off[j] = cum; cum += __popcll(mask[j]); }

    int wbase = 0;
    if (lane == 0) wbase = atomicAdd(&cnt, cum);   // one atomic per wave
    wbase = __shfl(wbase, 0);

    int* __restrict__ bucket = ws + N_TASKS + t * BUCKET_CAP;
    const unsigned long long lt = (lane == 63) ? ~0ull >> 1 : (1ull << lane) - 1;
#pragma unroll
    for (int u = 0; u < 4; ++u) {
#pragma unroll
        for (int c = 0; c < 4; ++c) {
            const int j = 4 * u + c;
            if ((mask[j] >> lane) & 1) {
                const int pos = wbase + off[j] + (int)__popcll(mask[j] & lt);
                bucket[pos] = (tid + 256 * u) * 4 + c;
            }
        }
    }
    __syncthreads();
    if (tid == 0) ws[t] = cnt;
}

__global__ __launch_bounds__(THREADS, 4) void mtal_mfma(
    const float* __restrict__ x, const float* __restrict__ emb,
    const int* __restrict__ ws, float* __restrict__ out)
{
    // XCD-aware decode: all 16 col-blocks of task t have bid%8 == t%8
    // -> same XCD -> W_t and gathered x rows stay in one L2.
    const int bid = blockIdx.x;
    const int t   = bid & 63;           // task id
    const int ct  = bid >> 6;           // col tile (16 outputs)

    const int lane  = threadIdx.x & 63;
    const int wv    = threadIdx.x >> 6; // wave 0..3, splits row tiles
    const int l15   = lane & 15;
    const int khalf = lane >> 4;        // 0..3
    const int col   = ct * 16 + l15;

    const float* __restrict__ wbase = emb + (size_t)t * FULL_EMBED;

    // B fragments: W[col][k], k = ks*32 + khalf*8 + j (32B contiguous/lane).
    // Issued before any dependency on ws so the mandatory emb HBM fetch
    // starts at wave entry.
    const float* __restrict__ wp = wbase + (size_t)col * IN_CH + khalf * 8;
    bf16x8 wf[8];
#pragma unroll
    for (int ks = 0; ks < 8; ++ks) {
        f32x4 a = *reinterpret_cast<const f32x4*>(wp + ks * 32);
        f32x4 b = *reinterpret_cast<const f32x4*>(wp + ks * 32 + 4);
        wf[ks] = cvt8(a, b);
    }
    const float biasv = wbase[W_SIZE + col];

    const int n = ws[t];                // uniform -> s_load
    if (n == 0) return;
    const int* __restrict__ rows = ws + N_TASKS + t * BUCKET_CAP;

    const int nt = (n + 15) >> 4;       // row tiles of 16
    for (int rt = wv; rt < nt; rt += 4) {
        const int ridx = rt * 16 + l15;
        const int row  = rows[ridx < n ? ridx : 0];   // clamp dup for tail
        const float* __restrict__ xr = x + (size_t)row * IN_CH + khalf * 8;

        bf16x8 af[8];
#pragma unroll
        for (int ks = 0; ks < 8; ++ks) {
            f32x4 a = *reinterpret_cast<const f32x4*>(xr + ks * 32);
            f32x4 b = *reinterpret_cast<const f32x4*>(xr + ks * 32 + 4);
            af[ks] = cvt8(a, b);
        }

        f32x4 acc = { biasv, biasv, biasv, biasv };
#pragma unroll
        for (int ks = 0; ks < 8; ++ks)
            acc = __builtin_amdgcn_mfma_f32_16x16x32_bf16(af[ks], wf[ks], acc, 0, 0, 0);

        // D layout: col = lane&15, row = khalf*4 + reg (verified m89 mapping).
        const int m0 = rt * 16 + khalf * 4;
#pragma unroll
        for (int r = 0; r < 4; ++r) {
            const int gm = m0 + r;
            // row index for gm is held by lane l15 == khalf*4 + r (same tile)
            const int grow = __shfl(row, khalf * 4 + r, 16);
            if (gm < n)
                out[(size_t)grow * OUT_CH + col] = acc[r];
        }
    }
}

extern "C" void kernel_launch(void* const* d_in, const int* in_sizes, int n_in,
                              void* d_out, int out_size, void* d_ws, size_t ws_size,
                              hipStream_t stream) {
    const float* x    = (const float*)d_in[0];
    const int*   tids = (const int*)d_in[1];
    const float* emb  = (const float*)d_in[2];
    float*       out  = (float*)d_out;
    int*         ws   = (int*)d_ws;
    const int B = in_sizes[1];   // 4096

    bucket_kernel<<<dim3(N_TASKS), dim3(256), 0, stream>>>(tids, ws, B);
    mtal_mfma<<<dim3(N_TASKS * NCOLT), dim3(THREADS), 0, stream>>>(
        x, emb, ws, out);
}

// Round 6
// 84.952 us; speedup vs baseline: 1.0433x; 1.0257x over previous
//
#include <hip/hip_runtime.h>
#include <hip/hip_bf16.h>

#define IN_CH 256
#define OUT_CH 256
#define N_TASKS 64
#define W_SIZE (OUT_CH * IN_CH)          // 65536
#define FULL_EMBED (W_SIZE + OUT_CH)     // 65792
#define NCOLT 16                         // 16 col tiles of 16 outputs

typedef __attribute__((ext_vector_type(8))) short bf16x8;
typedef __attribute__((ext_vector_type(4))) float f32x4;

static __device__ __forceinline__ short f2bf(float f) {
    union { __hip_bfloat16 h; short s; } u;
    u.h = __float2bfloat16(f);
    return u.s;
}

static __device__ __forceinline__ bf16x8 cvt8(f32x4 a, f32x4 b) {
    bf16x8 r;
    r[0] = f2bf(a.x); r[1] = f2bf(a.y); r[2] = f2bf(a.z); r[3] = f2bf(a.w);
    r[4] = f2bf(b.x); r[5] = f2bf(b.y); r[6] = f2bf(b.z); r[7] = f2bf(b.w);
    return r;
}

// One fused kernel: block (t, ct) scans task t's rows into LDS (ballot
// compaction, zero atomics) while its W-panel HBM loads are in flight,
// then runs the MFMA row loop.
__global__ __launch_bounds__(256, 4) void mtal_fused(
    const float* __restrict__ x, const int* __restrict__ tids,
    const float* __restrict__ emb, float* __restrict__ out, int B)
{
    __shared__ int rows[4096];
    __shared__ int swcnt[4];

    // XCD-aware decode: all 16 col-blocks of task t have bid%8 == t%8.
    const int bid = blockIdx.x;
    const int t   = bid & 63;            // task id
    const int ct  = bid >> 6;            // col tile (16 outputs)

    const int tid   = threadIdx.x;
    const int lane  = tid & 63;
    const int wv    = tid >> 6;          // wave 0..3
    const int l15   = lane & 15;
    const int khalf = lane >> 4;         // 0..3
    const int col   = ct * 16 + l15;

    const float* __restrict__ wbase = emb + (size_t)t * FULL_EMBED;

    // (1) tids loads first — the scan consumes these soonest.
    int4 v[4];
#pragma unroll
    for (int u = 0; u < 4; ++u)
        v[u] = reinterpret_cast<const int4*>(tids)[tid + 256 * u];

    // (2) W-panel + bias loads issued now, consumed only after the scan:
    // their ~HBM latency is hidden under the ballot compaction.
    const float* __restrict__ wp = wbase + (size_t)col * IN_CH + khalf * 8;
    f32x4 wraw[16];
#pragma unroll
    for (int ks = 0; ks < 8; ++ks) {
        wraw[2 * ks]     = *reinterpret_cast<const f32x4*>(wp + ks * 32);
        wraw[2 * ks + 1] = *reinterpret_cast<const f32x4*>(wp + ks * 32 + 4);
    }
    const float biasv = wbase[W_SIZE + col];

    // (3) ballot compaction of task-t rows into LDS. Masks are wave-uniform
    // (SGPR-resident); no LDS atomics; two barriers total.
    unsigned long long mask[16];
    int off[16];
    int cum = 0;
#pragma unroll
    for (int u = 0; u < 4; ++u) {
        mask[4 * u + 0] = __ballot(v[u].x == t);
        mask[4 * u + 1] = __ballot(v[u].y == t);
        mask[4 * u + 2] = __ballot(v[u].z == t);
        mask[4 * u + 3] = __ballot(v[u].w == t);
    }
#pragma unroll
    for (int j = 0; j < 16; ++j) { off[j] = cum; cum += __popcll(mask[j]); }

    if (lane == 0) swcnt[wv] = cum;
    __syncthreads();

    int base = 0;
#pragma unroll
    for (int w = 0; w < 4; ++w) base += (w < wv) ? swcnt[w] : 0;
    const int n = swcnt[0] + swcnt[1] + swcnt[2] + swcnt[3];

    const unsigned long long lt = (lane == 63) ? ~0ull >> 1 : (1ull << lane) - 1;
#pragma unroll
    for (int u = 0; u < 4; ++u) {
#pragma unroll
        for (int c = 0; c < 4; ++c) {
            const int j = 4 * u + c;
            if ((mask[j] >> lane) & 1) {
                const int pos = base + off[j] + (int)__popcll(mask[j] & lt);
                rows[pos] = (tid + 256 * u) * 4 + c;
            }
        }
    }
    __syncthreads();

    // (4) convert W to bf16 fragments (HBM latency long since covered).
    bf16x8 wf[8];
#pragma unroll
    for (int ks = 0; ks < 8; ++ks)
        wf[ks] = cvt8(wraw[2 * ks], wraw[2 * ks + 1]);

    if (n == 0) return;

    const int nt = (n + 15) >> 4;        // row tiles of 16
    for (int rt = wv; rt < nt; rt += 4) {
        const int ridx = rt * 16 + l15;
        const int row  = rows[ridx < n ? ridx : 0];   // clamp dup for tail
        const float* __restrict__ xr = x + (size_t)row * IN_CH + khalf * 8;

        bf16x8 af[8];
#pragma unroll
        for (int ks = 0; ks < 8; ++ks) {
            f32x4 a = *reinterpret_cast<const f32x4*>(xr + ks * 32);
            f32x4 b = *reinterpret_cast<const f32x4*>(xr + ks * 32 + 4);
            af[ks] = cvt8(a, b);
        }

        f32x4 acc = { biasv, biasv, biasv, biasv };
#pragma unroll
        for (int ks = 0; ks < 8; ++ks)
            acc = __builtin_amdgcn_mfma_f32_16x16x32_bf16(af[ks], wf[ks], acc, 0, 0, 0);

        // D layout: col = lane&15, row = khalf*4 + reg (verified m89 mapping).
        const int m0 = rt * 16 + khalf * 4;
#pragma unroll
        for (int r = 0; r < 4; ++r) {
            const int gm = m0 + r;
            const int grow = __shfl(row, khalf * 4 + r, 16);
            if (gm < n)
                out[(size_t)grow * OUT_CH + col] = acc[r];
        }
    }
}

extern "C" void kernel_launch(void* const* d_in, const int* in_sizes, int n_in,
                              void* d_out, int out_size, void* d_ws, size_t ws_size,
                              hipStream_t stream) {
    const float* x    = (const float*)d_in[0];
    const int*   tids = (const int*)d_in[1];
    const float* emb  = (const float*)d_in[2];
    float*       out  = (float*)d_out;
    const int B = in_sizes[1];   // 4096

    mtal_fused<<<dim3(N_TASKS * NCOLT), dim3(256), 0, stream>>>(
        x, tids, emb, out, B);
}